// Round 11
// baseline (126.781 us; speedup 1.0000x reference)
//
#include <hip/hip_runtime.h>
#include <stdint.h>

#define NH 8
#define HD 64
#define KVB 64
#define TOKS 1536      // 3*NH*HD floats per token
#define OUTS 512       // NH*HD floats per token
#define NSEQ 64
#define NBLK 1152      // 4 jobs/block; max jobs = 8*(16384/32 + 64) = 4608

typedef __attribute__((ext_vector_type(8))) short bf16x8;
typedef __attribute__((ext_vector_type(16))) float f32x16;

#define QSCALE 0.18033688f   // 0.125 * log2(e): softmax in exp2 domain

__device__ __forceinline__ unsigned cvt_pk(float lo, float hi) {
  unsigned r;
  asm("v_cvt_pk_bf16_f32 %0, %1, %2" : "=v"(r) : "v"(lo), "v"(hi));
  return r;
}
__device__ __forceinline__ float xmax32(float x) {
  float y;
  asm volatile("v_mov_b32 %0, %1" : "=v"(y) : "v"(x));
  asm volatile("v_permlane32_swap_b32 %0, %1" : "+v"(x), "+v"(y));
  return fmaxf(x, y);
}
__device__ __forceinline__ float xadd32(float x) {
  float y;
  asm volatile("v_mov_b32 %0, %1" : "=v"(y) : "v"(x));
  asm volatile("v_permlane32_swap_b32 %0, %1" : "+v"(x), "+v"(y));
  return x + y;
}
__device__ __forceinline__ void plswap(unsigned &a, unsigned &b) {
  asm volatile("v_permlane32_swap_b32 %0, %1" : "+v"(a), "+v"(b));
}
// P-fragment (B-operand, 16 keys x 32 q) from 8 consecutive S^T regs
__device__ __forceinline__ bf16x8 mkfrag(const f32x16& s, int base) {
  unsigned a01 = cvt_pk(s[base + 0], s[base + 1]);
  unsigned a23 = cvt_pk(s[base + 2], s[base + 3]);
  unsigned a45 = cvt_pk(s[base + 4], s[base + 5]);
  unsigned a67 = cvt_pk(s[base + 6], s[base + 7]);
  plswap(a01, a45);
  plswap(a23, a67);
  union { unsigned u[4]; bf16x8 v; } pf;
  pf.u[0] = a01; pf.u[1] = a23; pf.u[2] = a45; pf.u[3] = a67;
  return pf.v;
}
__device__ __forceinline__ bf16x8 pack8(float4 a, float4 b) {
  union { unsigned u[4]; bf16x8 v; } k;
  k.u[0] = cvt_pk(a.x, a.y); k.u[1] = cvt_pk(a.z, a.w);
  k.u[2] = cvt_pk(b.x, b.y); k.u[3] = cvt_pk(b.z, b.w);
  return k.v;
}

// Fully independent waves: no LDS, no barriers. One wave = 32 q-rows of one
// (seq, head). K frags gathered per-lane; V^T frags from coalesced scalar
// loads (lane index = d = contiguous axis).
__global__ __launch_bounds__(256, 3)
void varlen_attn_iw(const float* __restrict__ qkv, const int* __restrict__ cu,
                    float* __restrict__ out) {
  const int lane = threadIdx.x & 63;
  const int wv = __builtin_amdgcn_readfirstlane(threadIdx.x >> 6);
  const int l31 = lane & 31, hi = lane >> 5;

  // ---- job scan: job -> (seq b, band, head h); uniform -> scalarizes ----
  int job = blockIdx.x * 4 + wv;
  int start = 0, len = 0, bfound = 0;
  {
    int r = job, prev = cu[0];
    int b = 0;
    for (; b < NSEQ; ++b) {
      const int nxt = cu[b + 1];
      const int L = nxt - prev;
      const int c = (((L + 31) >> 5) << 3);   // ceil(L/32) * 8 jobs
      if (r < c) { start = prev; len = L; break; }
      r -= c;
      prev = nxt;
    }
    if (b == NSEQ) return;   // beyond total jobs
    bfound = r;
  }
  const int band = bfound >> 3, h = bfound & 7;
  const int q0 = band * 32;
  const int lm1 = len - 1;
  const int qrow = q0 + l31;

  // ---- Q B-frag (col q = l31, k-elem d = dc*16 + hi*8 + j), exp2-scaled ----
  bf16x8 qbf[4];
  {
    const float* qp = qkv + (size_t)(start + min(qrow, lm1)) * TOKS + h * HD;
#pragma unroll
    for (int dc = 0; dc < 4; ++dc) {
      const float4 f0 = *(const float4*)(qp + dc * 16 + hi * 8);
      const float4 f1 = *(const float4*)(qp + dc * 16 + hi * 8 + 4);
      union { unsigned u[4]; bf16x8 v; } qq;
      qq.u[0] = cvt_pk(f0.x * QSCALE, f0.y * QSCALE);
      qq.u[1] = cvt_pk(f0.z * QSCALE, f0.w * QSCALE);
      qq.u[2] = cvt_pk(f1.x * QSCALE, f1.y * QSCALE);
      qq.u[3] = cvt_pk(f1.z * QSCALE, f1.w * QSCALE);
      qbf[dc] = qq.v;
    }
  }

  f32x16 o0, o1;   // O^T acc: d-groups 0..31 / 32..63, col q = l31
#pragma unroll
  for (int i = 0; i < 16; ++i) { o0[i] = 0.f; o1[i] = 0.f; }
  float mrun = -1e30f, sden = 0.f;

  const int nt = (len + KVB - 1) / KVB;
  // invariant base for V scalar loads: d = l31 (o0) / 32+l31 (o1)
  const float* vbase = qkv + (size_t)start * TOKS + h * HD + 1024 + l31;

  for (int tt = 0; tt < nt; ++tt) {
    const int kv0 = tt * KVB;

    // ---- S^T = K x Q: K A-frags gathered per-lane (row = key = l31) ----
    const float* kA = qkv + (size_t)(start + min(kv0 + l31, lm1)) * TOKS + h * HD + 512;
    const float* kB = qkv + (size_t)(start + min(kv0 + 32 + l31, lm1)) * TOKS + h * HD + 512;
    f32x16 s0, s1;
#pragma unroll
    for (int i = 0; i < 16; ++i) { s0[i] = 0.f; s1[i] = 0.f; }
#pragma unroll
    for (int dc = 0; dc < 4; ++dc) {
      const float4 a0 = *(const float4*)(kA + dc * 16 + hi * 8);
      const float4 a1 = *(const float4*)(kA + dc * 16 + hi * 8 + 4);
      const float4 c0 = *(const float4*)(kB + dc * 16 + hi * 8);
      const float4 c1 = *(const float4*)(kB + dc * 16 + hi * 8 + 4);
      s0 = __builtin_amdgcn_mfma_f32_32x32x16_bf16(pack8(a0, a1), qbf[dc], s0, 0, 0, 0);
      s1 = __builtin_amdgcn_mfma_f32_32x32x16_bf16(pack8(c0, c1), qbf[dc], s1, 0, 0, 0);
    }

    // ---- mask tail keys ----
    if (kv0 + KVB > len) {
      const int kb = kv0 + 4 * hi;
#pragma unroll
      for (int r = 0; r < 16; ++r) {
        const int ko = (r & 3) + 8 * (r >> 2);
        if (kb + ko >= len) s0[r] = -1e9f;
        if (kb + 32 + ko >= len) s1[r] = -1e9f;
      }
    }

    // ---- tree max + lane-local online softmax (exp2 domain) ----
    float pa[8];
#pragma unroll
    for (int i = 0; i < 8; ++i)
      pa[i] = fmaxf(fmaxf(s0[2 * i], s0[2 * i + 1]), fmaxf(s1[2 * i], s1[2 * i + 1]));
    float mx = fmaxf(fmaxf(fmaxf(pa[0], pa[1]), fmaxf(pa[2], pa[3])),
                     fmaxf(fmaxf(pa[4], pa[5]), fmaxf(pa[6], pa[7])));
    mx = xmax32(mx);
    const float mn = fmaxf(mrun, mx);
    const float cc = exp2f(mrun - mn);
    mrun = mn;
#pragma unroll
    for (int r = 0; r < 16; ++r) {
      s0[r] = exp2f(s0[r] - mn);
      s1[r] = exp2f(s1[r] - mn);
    }
    float u[4] = {0.f, 0.f, 0.f, 0.f};
#pragma unroll
    for (int r = 0; r < 16; ++r) u[r & 3] += s0[r] + s1[r];
    float rs = (u[0] + u[1]) + (u[2] + u[3]);
    rs = xadd32(rs);
    sden = sden * cc + rs;
#pragma unroll
    for (int i = 0; i < 16; ++i) { o0[i] *= cc; o1[i] *= cc; }

    // ---- PV: O^T += V^T x P^T; V^T A-frags from coalesced scalar loads ----
    // lane needs V[key = kc*16 + hi*8 + j][d = l31 (+32)]; per load instr the
    // wave's 32 lanes of each half read 32 consecutive floats (2 lines).
#pragma unroll
    for (int kc = 0; kc < 4; ++kc) {
      const int kb2 = kv0 + kc * 16 + hi * 8;
      unsigned w0[4], w1[4];
#pragma unroll
      for (int jj = 0; jj < 4; ++jj) {
        const float* va = vbase + (size_t)min(kb2 + 2 * jj, lm1) * TOKS;
        const float* vb = vbase + (size_t)min(kb2 + 2 * jj + 1, lm1) * TOKS;
        const float f0 = va[0], f1 = vb[0];
        const float g0 = va[32], g1 = vb[32];
        w0[jj] = cvt_pk(f0, f1);
        w1[jj] = cvt_pk(g0, g1);
      }
      union { unsigned u[4]; bf16x8 v; } v0, v1;
      v0.u[0] = w0[0]; v0.u[1] = w0[1]; v0.u[2] = w0[2]; v0.u[3] = w0[3];
      v1.u[0] = w1[0]; v1.u[1] = w1[1]; v1.u[2] = w1[2]; v1.u[3] = w1[3];
      const bf16x8 pf = mkfrag(kc < 2 ? s0 : s1, (kc & 1) * 8);
      o0 = __builtin_amdgcn_mfma_f32_32x32x16_bf16(v0.v, pf, o0, 0, 0, 0);
      o1 = __builtin_amdgcn_mfma_f32_32x32x16_bf16(v1.v, pf, o1, 0, 0, 0);
    }
  }

  // ---- epilogue: O^T reg r -> d = (r&3) + 8*(r>>2) + 4*hi (+32 for o1) ----
  if (qrow < len) {
    const float inv = 1.f / sden;
    float* orow = out + (size_t)(start + qrow) * OUTS + h * HD;
#pragma unroll
    for (int q4 = 0; q4 < 4; ++q4) {
      float4 t0, t1;
      t0.x = o0[q4 * 4 + 0] * inv; t0.y = o0[q4 * 4 + 1] * inv;
      t0.z = o0[q4 * 4 + 2] * inv; t0.w = o0[q4 * 4 + 3] * inv;
      t1.x = o1[q4 * 4 + 0] * inv; t1.y = o1[q4 * 4 + 1] * inv;
      t1.z = o1[q4 * 4 + 2] * inv; t1.w = o1[q4 * 4 + 3] * inv;
      *(float4*)(orow + 8 * q4 + 4 * hi) = t0;
      *(float4*)(orow + 32 + 8 * q4 + 4 * hi) = t1;
    }
  }
}

extern "C" void kernel_launch(void* const* d_in, const int* in_sizes, int n_in,
                              void* d_out, int out_size, void* d_ws, size_t ws_size,
                              hipStream_t stream) {
  const float* qkv = (const float*)d_in[0];
  const int* cu = (const int*)d_in[1];
  float* out = (float*)d_out;
  varlen_attn_iw<<<NBLK, 256, 0, stream>>>(qkv, cu, out);
}